// Round 12
// baseline (200.187 us; speedup 1.0000x reference)
//
#include <hip/hip_runtime.h>

// W2LossConst: per-trace  sum_i w_i * (t_i - spline_b(F_b[t_i]))^2 * f_b[t_i] * dt
//   F = cumulative trapezoid of f; thread-local exact recurrence
//   F += 0.5*dt*(f[i-1]+f[i]) seeded from a block prefix-scan of f sums.
//
// R10 post-mortem: 512x16 @ VGPR=100 -> 4 waves/SIMD, latency-bound (HBM 10%,
// VALU 27%, occ 18%). Fix: back to 1024 threads x 8 elems (R2's occupancy
// point: half the per-thread serial chain, 2x waves) KEEPING the two-interval
// register window (cndmask select, no LDS / no divergence in the hot loop).
// Live-state audit ~48 VGPR -> __launch_bounds__(1024,8) caps at 64 safely
// (R6's spill was demand~100 vs cap 64; tripwire = WRITE_SIZE ballooning).

#define NT 8192
#define K 128
#define NTHREADS 1024
#define ELEMS (NT / NTHREADS)   // 8 samples per thread
#define NWAVES (NTHREADS / 64)  // 16 waves
#define LUTG 256                // uniform search-LUT cells over [0,1]

__global__ __launch_bounds__(NTHREADS, 8) void w2loss_kernel(
    const float* __restrict__ f,
    const float* __restrict__ t,
    const float* __restrict__ knots,
    const float* __restrict__ coeffs,
    float* __restrict__ out)
{
    const int b    = blockIdx.x;
    const int tid  = threadIdx.x;
    const int lane = tid & 63;
    const int wave = tid >> 6;

    __shared__ float  s_knots[K];
    __shared__ float4 s_coeffs[K - 1];
    __shared__ int    s_lut[LUTG];
    __shared__ float  s_wsum[NWAVES];
    __shared__ float  s_wred[NWAVES];
    __shared__ float  s_f0;

    // ---- stage per-trace spline tables in LDS ----
    if (tid < K) s_knots[tid] = knots[(size_t)b * K + tid];
    if (tid < K - 1)
        s_coeffs[tid] =
            reinterpret_cast<const float4*>(coeffs + (size_t)b * (K - 1) * 4)[tid];

    // ---- load this thread's 8 contiguous f samples into registers ----
    const float4* fb4 =
        reinterpret_cast<const float4*>(f + (size_t)b * NT + tid * ELEMS);
    float fv[ELEMS];
#pragma unroll
    for (int i = 0; i < ELEMS / 4; ++i) {
        float4 v = fb4[i];
        fv[4 * i + 0] = v.x; fv[4 * i + 1] = v.y;
        fv[4 * i + 2] = v.z; fv[4 * i + 3] = v.w;
    }

    float local = 0.f;
#pragma unroll
    for (int i = 0; i < ELEMS; ++i) local += fv[i];

    // ---- inclusive wave scan of per-thread sums ----
    float scan = local;
#pragma unroll
    for (int d = 1; d < 64; d <<= 1) {
        float up = __shfl_up(scan, d, 64);
        if (lane >= d) scan += up;
    }
    if (lane == 63) s_wsum[wave] = scan;
    if (tid == 0)  s_f0 = fv[0];
    __syncthreads();                      // knots, coeffs, wsum, f0 visible

    // ---- build uniform search LUT: lut[g] = max idx with knots[idx] <= g/G ----
    if (tid < LUTG) {
        float gval = (float)tid * (1.0f / (float)LUTG);
        int p = 0;
#pragma unroll
        for (int step = 64; step >= 1; step >>= 1) {
            int np = p + step;
            if (np <= K - 1 && s_knots[np] <= gval) p = np;
        }
        s_lut[tid] = p;                   // always <= K-2 (knots[K-1] > 255/256)
    }
    __syncthreads();                      // LUT visible

    // ---- waveoff: one LDS read + shfl scan over the 16 wave sums ----
    float wv = (lane < NWAVES) ? s_wsum[lane] : 0.f;
#pragma unroll
    for (int d = 1; d < NWAVES; d <<= 1) {
        float up = __shfl_up(wv, d, 64);
        if (lane >= d) wv += up;
    }
    const float waveoff = (wave == 0) ? 0.f : __shfl(wv, wave - 1, 64);

    const float f0      = s_f0;
    const float dt      = t[1] - t[0];    // uniform grid; t_i == i*dt
    const float half_dt = 0.5f * dt;

    // thread's first-sample CDF value from the block scan
    const float S_incl_first = waveoff + (scan - local) + fv[0];
    float F = (S_incl_first - 0.5f * (f0 + fv[0])) * dt;

    const int   base = tid * ELEMS;
    const float tb   = (float)base * dt;

    // ---- two-interval register window [i0, i0+1] ----
    int g  = (int)(F * (float)LUTG);
    g      = g > (LUTG - 1) ? (LUTG - 1) : (g < 0 ? 0 : g);
    int i0 = s_lut[g];
    while (i0 < K - 2 && s_knots[i0 + 1] <= F) ++i0;
    float  kn0_lo = s_knots[i0];
    float  kn0_hi = s_knots[i0 + 1];
    float4 c0     = s_coeffs[i0];
    int    j1     = (i0 < K - 2) ? i0 + 1 : K - 2;
    float4 c1     = s_coeffs[j1];
    float  kn1_hi = (i0 + 2 <= K - 1) ? s_knots[i0 + 2] : 3.4e38f;

    float acc0, acc1 = 0.f, term_first, term_last = 0.f;
    {   // first sample: walk guarantees F in [kn0_lo, kn0_hi)
        float dx = F - kn0_lo;
        float sp = c0.x + dx * (c0.y + dx * (c0.z + dx * c0.w));
        float d0 = tb - sp;
        term_first = d0 * d0 * fv[0];
        acc0 = term_first;
    }

#pragma unroll
    for (int i = 1; i < ELEMS; ++i) {
        F = fmaf(fv[i - 1] + fv[i], half_dt, F);   // exact trapezoid recurrence

        if (kn1_hi <= F) {                         // rare: window exhausted
            int idx = i0 + 2;
            while (idx < K - 2 && s_knots[idx + 1] <= F) ++idx;
            i0     = idx > K - 2 ? K - 2 : idx;    // clamp (F ~ 1 edge)
            kn0_lo = s_knots[i0];
            kn0_hi = s_knots[i0 + 1];
            c0     = s_coeffs[i0];
            j1     = (i0 < K - 2) ? i0 + 1 : K - 2;
            c1     = s_coeffs[j1];
            kn1_hi = (i0 + 2 <= K - 1) ? s_knots[i0 + 2] : 3.4e38f;
        }

        // branchless interval select (cndmask, no LDS)
        bool  use1 = (kn0_hi <= F);
        float klo  = use1 ? kn0_hi : kn0_lo;
        float cx   = use1 ? c1.x : c0.x;
        float cy   = use1 ? c1.y : c0.y;
        float cz   = use1 ? c1.z : c0.z;
        float cw   = use1 ? c1.w : c0.w;

        float dx = F - klo;
        float sp = cx + dx * (cy + dx * (cz + dx * cw));
        float tt = fmaf((float)i, dt, tb);
        float d  = tt - sp;
        float term = d * d * fv[i];
        if (i & 1) acc1 += term; else acc0 += term;   // 2 chains for ILP
        if (i == ELEMS - 1) term_last = term;
    }

    // endpoint trapezoid weights (0.5) applied as post-corrections
    float acc = acc0 + acc1;
    if (base == 0)          acc -= 0.5f * term_first;
    if (base + ELEMS == NT) acc -= 0.5f * term_last;

    // ---- block reduction ----
#pragma unroll
    for (int d = 32; d >= 1; d >>= 1) acc += __shfl_down(acc, d, 64);
    if (lane == 0) s_wred[wave] = acc;
    __syncthreads();
    if (tid == 0) {
        float r = 0.f;
#pragma unroll
        for (int w = 0; w < NWAVES; ++w) r += s_wred[w];
        out[b] = r * dt;
    }
}

extern "C" void kernel_launch(void* const* d_in, const int* in_sizes, int n_in,
                              void* d_out, int out_size, void* d_ws, size_t ws_size,
                              hipStream_t stream) {
    const float* f      = (const float*)d_in[0];
    const float* t      = (const float*)d_in[1];
    const float* knots  = (const float*)d_in[2];
    const float* coeffs = (const float*)d_in[3];
    float* out          = (float*)d_out;

    const int Btr = in_sizes[0] / NT;   // 2048 traces
    w2loss_kernel<<<Btr, NTHREADS, 0, stream>>>(f, t, knots, coeffs, out);
}

// Round 15
// 119.194 us; speedup vs baseline: 1.6795x; 1.6795x over previous
//
#include <hip/hip_runtime.h>

// W2LossConst: per-trace  sum_i w_i * (t_i - spline_b(F_b[t_i]))^2 * f_b[t_i] * dt
//   F = cumulative trapezoid of f; thread-local exact recurrence
//   F += 0.5*dt*(f[i-1]+f[i]) seeded from a block prefix-scan of f sums.
//
// R12 post-mortem: hipcc's VGPR cap from __launch_bounds__(B,w) is 256/w
// (empirical: (512,4)->64, (1024,8)->32), NOT pool/waves. (1024,8) caged the
// kernel at 32 VGPR -> 287MB scratch writes, 121us. Fix: (1024,4) -> cap 64;
// demand ~48-56 fits; <=64 VGPR still allows 8 waves/SIMD (2 blocks/CU).
// Hot loop unchanged: two-interval register window, cndmask select, no LDS.

#define NT 8192
#define K 128
#define NTHREADS 1024
#define ELEMS (NT / NTHREADS)   // 8 samples per thread
#define NWAVES (NTHREADS / 64)  // 16 waves
#define LUTG 256                // uniform search-LUT cells over [0,1]

__global__ __launch_bounds__(NTHREADS, 4) void w2loss_kernel(
    const float* __restrict__ f,
    const float* __restrict__ t,
    const float* __restrict__ knots,
    const float* __restrict__ coeffs,
    float* __restrict__ out)
{
    const int b    = blockIdx.x;
    const int tid  = threadIdx.x;
    const int lane = tid & 63;
    const int wave = tid >> 6;

    __shared__ float  s_knots[K];
    __shared__ float4 s_coeffs[K - 1];
    __shared__ int    s_lut[LUTG];
    __shared__ float  s_wsum[NWAVES];
    __shared__ float  s_wred[NWAVES];
    __shared__ float  s_f0;

    // ---- stage per-trace spline tables in LDS ----
    if (tid < K) s_knots[tid] = knots[(size_t)b * K + tid];
    if (tid < K - 1)
        s_coeffs[tid] =
            reinterpret_cast<const float4*>(coeffs + (size_t)b * (K - 1) * 4)[tid];

    // ---- load this thread's 8 contiguous f samples into registers ----
    const float4* fb4 =
        reinterpret_cast<const float4*>(f + (size_t)b * NT + tid * ELEMS);
    float fv[ELEMS];
#pragma unroll
    for (int i = 0; i < ELEMS / 4; ++i) {
        float4 v = fb4[i];
        fv[4 * i + 0] = v.x; fv[4 * i + 1] = v.y;
        fv[4 * i + 2] = v.z; fv[4 * i + 3] = v.w;
    }

    float local = 0.f;
#pragma unroll
    for (int i = 0; i < ELEMS; ++i) local += fv[i];

    // ---- inclusive wave scan of per-thread sums ----
    float scan = local;
#pragma unroll
    for (int d = 1; d < 64; d <<= 1) {
        float up = __shfl_up(scan, d, 64);
        if (lane >= d) scan += up;
    }
    if (lane == 63) s_wsum[wave] = scan;
    if (tid == 0)  s_f0 = fv[0];
    __syncthreads();                      // knots, coeffs, wsum, f0 visible

    // ---- build uniform search LUT: lut[g] = max idx with knots[idx] <= g/G ----
    if (tid < LUTG) {
        float gval = (float)tid * (1.0f / (float)LUTG);
        int p = 0;
#pragma unroll
        for (int step = 64; step >= 1; step >>= 1) {
            int np = p + step;
            if (np <= K - 1 && s_knots[np] <= gval) p = np;
        }
        s_lut[tid] = p;                   // always <= K-2 (knots[K-1] > 255/256)
    }
    __syncthreads();                      // LUT visible

    // ---- waveoff: one LDS read + shfl scan over the 16 wave sums ----
    float wv = (lane < NWAVES) ? s_wsum[lane] : 0.f;
#pragma unroll
    for (int d = 1; d < NWAVES; d <<= 1) {
        float up = __shfl_up(wv, d, 64);
        if (lane >= d) wv += up;
    }
    const float waveoff = (wave == 0) ? 0.f : __shfl(wv, wave - 1, 64);

    const float f0      = s_f0;
    const float dt      = t[1] - t[0];    // uniform grid; t_i == i*dt
    const float half_dt = 0.5f * dt;

    // thread's first-sample CDF value from the block scan
    const float S_incl_first = waveoff + (scan - local) + fv[0];
    float F = (S_incl_first - 0.5f * (f0 + fv[0])) * dt;

    const int   base = tid * ELEMS;
    const float tb   = (float)base * dt;

    // ---- two-interval register window [i0, i0+1] ----
    int g  = (int)(F * (float)LUTG);
    g      = g > (LUTG - 1) ? (LUTG - 1) : (g < 0 ? 0 : g);
    int i0 = s_lut[g];
    while (i0 < K - 2 && s_knots[i0 + 1] <= F) ++i0;
    float  kn0_lo = s_knots[i0];
    float  kn0_hi = s_knots[i0 + 1];
    float4 c0     = s_coeffs[i0];
    int    j1     = (i0 < K - 2) ? i0 + 1 : K - 2;
    float4 c1     = s_coeffs[j1];
    float  kn1_hi = (i0 + 2 <= K - 1) ? s_knots[i0 + 2] : 3.4e38f;

    float acc0, acc1 = 0.f, term_first, term_last = 0.f;
    {   // first sample: walk guarantees F in [kn0_lo, kn0_hi)
        float dx = F - kn0_lo;
        float sp = c0.x + dx * (c0.y + dx * (c0.z + dx * c0.w));
        float d0 = tb - sp;
        term_first = d0 * d0 * fv[0];
        acc0 = term_first;
    }

#pragma unroll
    for (int i = 1; i < ELEMS; ++i) {
        F = fmaf(fv[i - 1] + fv[i], half_dt, F);   // exact trapezoid recurrence

        if (kn1_hi <= F) {                         // rare: window exhausted
            int idx = i0 + 2;
            while (idx < K - 2 && s_knots[idx + 1] <= F) ++idx;
            i0     = idx > K - 2 ? K - 2 : idx;    // clamp (F ~ 1 edge)
            kn0_lo = s_knots[i0];
            kn0_hi = s_knots[i0 + 1];
            c0     = s_coeffs[i0];
            j1     = (i0 < K - 2) ? i0 + 1 : K - 2;
            c1     = s_coeffs[j1];
            kn1_hi = (i0 + 2 <= K - 1) ? s_knots[i0 + 2] : 3.4e38f;
        }

        // branchless interval select (cndmask, no LDS)
        bool  use1 = (kn0_hi <= F);
        float klo  = use1 ? kn0_hi : kn0_lo;
        float cx   = use1 ? c1.x : c0.x;
        float cy   = use1 ? c1.y : c0.y;
        float cz   = use1 ? c1.z : c0.z;
        float cw   = use1 ? c1.w : c0.w;

        float dx = F - klo;
        float sp = cx + dx * (cy + dx * (cz + dx * cw));
        float tt = fmaf((float)i, dt, tb);
        float d  = tt - sp;
        float term = d * d * fv[i];
        if (i & 1) acc1 += term; else acc0 += term;   // 2 chains for ILP
        if (i == ELEMS - 1) term_last = term;
    }

    // endpoint trapezoid weights (0.5) applied as post-corrections
    float acc = acc0 + acc1;
    if (base == 0)          acc -= 0.5f * term_first;
    if (base + ELEMS == NT) acc -= 0.5f * term_last;

    // ---- block reduction ----
#pragma unroll
    for (int d = 32; d >= 1; d >>= 1) acc += __shfl_down(acc, d, 64);
    if (lane == 0) s_wred[wave] = acc;
    __syncthreads();
    if (tid == 0) {
        float r = 0.f;
#pragma unroll
        for (int w = 0; w < NWAVES; ++w) r += s_wred[w];
        out[b] = r * dt;
    }
}

extern "C" void kernel_launch(void* const* d_in, const int* in_sizes, int n_in,
                              void* d_out, int out_size, void* d_ws, size_t ws_size,
                              hipStream_t stream) {
    const float* f      = (const float*)d_in[0];
    const float* t      = (const float*)d_in[1];
    const float* knots  = (const float*)d_in[2];
    const float* coeffs = (const float*)d_in[3];
    float* out          = (float*)d_out;

    const int Btr = in_sizes[0] / NT;   // 2048 traces
    w2loss_kernel<<<Btr, NTHREADS, 0, stream>>>(f, t, knots, coeffs, out);
}

// Round 16
// 105.504 us; speedup vs baseline: 1.8974x; 1.1298x over previous
//
#include <hip/hip_runtime.h>

// W2LossConst — wave-per-trace, barrier-free main loop.
//   F = cumtrap(f) == (S_incl(i) - 0.5*(f0 + f_i))*dt  (exact identity).
// R15 post-mortem: barrier-coupled 1024-thread blocks serialize ~13k-cycle
// critical paths x 8 blocks/CU = 43us regardless of occupancy config.
// Fix: 1 wave = 1 trace (2048 independent waves), chunked 8 x (64 lanes x 16
// samples): prefetch -> wave shfl-scan -> LUT recenter -> 2-interval cndmask
// eval. Tables in per-wave LDS slice; __syncthreads only at setup; wave shfl
// reduce at end. All traces run concurrently -> time ~ one wave's chain.

#define NT 8192
#define K 128
#define NTHREADS 256
#define WPB (NTHREADS / 64)      // 4 waves (=4 traces) per block
#define PER_LANE 16
#define CHUNK (64 * PER_LANE)    // 1024 samples per chunk
#define NCHUNK (NT / CHUNK)      // 8 chunks
#define LUTG 256

__global__ __launch_bounds__(NTHREADS) void w2loss_kernel(
    const float* __restrict__ f,
    const float* __restrict__ t,
    const float* __restrict__ knots,
    const float* __restrict__ coeffs,
    float* __restrict__ out)
{
    const int tid   = threadIdx.x;
    const int ln    = tid & 63;
    const int w     = tid >> 6;
    const int trace = blockIdx.x * WPB + w;

    __shared__ float  s_knots[WPB][K];
    __shared__ float4 s_coeffs[WPB][K - 1];
    __shared__ int    s_lut[WPB][LUTG];

    // ---- stage this wave's spline tables into its LDS slice ----
    for (int j = ln; j < K; j += 64)
        s_knots[w][j] = knots[(size_t)trace * K + j];
    const float4* cf =
        reinterpret_cast<const float4*>(coeffs + (size_t)trace * (K - 1) * 4);
    for (int j = ln; j < K - 1; j += 64)
        s_coeffs[w][j] = cf[j];
    __syncthreads();

    // ---- uniform search LUT: lut[g] = max idx with knots[idx] <= g/G ----
#pragma unroll
    for (int q = 0; q < LUTG / 64; ++q) {
        int   cell = q * 64 + ln;
        float gval = (float)cell * (1.0f / (float)LUTG);
        int   p    = 0;
#pragma unroll
        for (int step = 64; step >= 1; step >>= 1) {
            int np = p + step;
            if (np <= K - 1 && s_knots[w][np] <= gval) p = np;
        }
        s_lut[w][cell] = p;              // <= K-2 (knots[K-1] > 255/256)
    }
    __syncthreads();

    const float  dt = t[1] - t[0];       // uniform grid; t_i == i*dt
    const float* fb = f + (size_t)trace * NT;

    // ---- preload chunk 0 (lane owns 16 contiguous samples) ----
    float4 a0, a1, a2, a3;
    {
        const float4* p4 = reinterpret_cast<const float4*>(fb) + ln * (PER_LANE / 4);
        a0 = p4[0]; a1 = p4[1]; a2 = p4[2]; a3 = p4[3];
    }
    const float f0 = __shfl(a0.x, 0, 64);   // trace's first sample

    float carry = 0.f, acc = 0.f, term_first = 0.f, term_last = 0.f;

    for (int c = 0; c < NCHUNK; ++c) {
        // prefetch next chunk (latency hides under this chunk's work)
        float4 b0, b1, b2, b3;
        if (c + 1 < NCHUNK) {
            const float4* p4 =
                reinterpret_cast<const float4*>(fb + (c + 1) * CHUNK) + ln * (PER_LANE / 4);
            b0 = p4[0]; b1 = p4[1]; b2 = p4[2]; b3 = p4[3];
        } else {
            b0 = a0; b1 = a1; b2 = a2; b3 = a3;
        }

        float fv[PER_LANE];
        fv[0]=a0.x; fv[1]=a0.y; fv[2]=a0.z; fv[3]=a0.w;
        fv[4]=a1.x; fv[5]=a1.y; fv[6]=a1.z; fv[7]=a1.w;
        fv[8]=a2.x; fv[9]=a2.y; fv[10]=a2.z; fv[11]=a2.w;
        fv[12]=a3.x; fv[13]=a3.y; fv[14]=a3.z; fv[15]=a3.w;

        float psum = 0.f;
#pragma unroll
        for (int k = 0; k < PER_LANE; ++k) psum += fv[k];

        // wave inclusive scan of per-lane sums
        float scan = psum;
#pragma unroll
        for (int d = 1; d < 64; d <<= 1) {
            float up = __shfl_up(scan, d, 64);
            if (ln >= d) scan += up;
        }
        const float excl = carry + (scan - psum);  // S_excl at lane's first sample
        carry += __shfl(scan, 63, 64);             // chunk total

        // ---- recenter two-interval window at lane's first sample ----
        float Ffirst = (excl + fv[0] - 0.5f * (f0 + fv[0])) * dt;
        int g  = (int)(Ffirst * (float)LUTG);
        g      = g > (LUTG - 1) ? (LUTG - 1) : (g < 0 ? 0 : g);
        int i0 = s_lut[w][g];
        while (i0 < K - 2 && s_knots[w][i0 + 1] <= Ffirst) ++i0;
        float  kn0_lo = s_knots[w][i0];
        float  kn0_hi = s_knots[w][i0 + 1];
        float4 c0     = s_coeffs[w][i0];
        int    j1     = (i0 < K - 2) ? i0 + 1 : K - 2;
        float4 c1     = s_coeffs[w][j1];
        float  kn1_hi = (i0 + 2 <= K - 1) ? s_knots[w][i0 + 2] : 3.4e38f;

        const float tbase = (float)(c * CHUNK + ln * PER_LANE) * dt;
        float s = 0.f;

#pragma unroll
        for (int k = 0; k < PER_LANE; ++k) {
            s += fv[k];
            float F = (excl + s - 0.5f * (f0 + fv[k])) * dt;

            if (kn1_hi <= F) {                     // rare: window exhausted
                int idx = i0 + 2;
                while (idx < K - 2 && s_knots[w][idx + 1] <= F) ++idx;
                i0     = idx > K - 2 ? K - 2 : idx;
                kn0_lo = s_knots[w][i0];
                kn0_hi = s_knots[w][i0 + 1];
                c0     = s_coeffs[w][i0];
                j1     = (i0 < K - 2) ? i0 + 1 : K - 2;
                c1     = s_coeffs[w][j1];
                kn1_hi = (i0 + 2 <= K - 1) ? s_knots[w][i0 + 2] : 3.4e38f;
            }

            // branchless interval select (cndmask, no LDS)
            bool  use1 = (kn0_hi <= F);
            float klo  = use1 ? kn0_hi : kn0_lo;
            float cx   = use1 ? c1.x : c0.x;
            float cy   = use1 ? c1.y : c0.y;
            float cz   = use1 ? c1.z : c0.z;
            float cw   = use1 ? c1.w : c0.w;

            float dx = F - klo;
            float sp = cx + dx * (cy + dx * (cz + dx * cw));
            float tt = fmaf((float)k, dt, tbase);
            float d  = tt - sp;
            float term = d * d * fv[k];
            acc += term;
            if (k == 0 && c == 0)                     term_first = term;
            if (k == PER_LANE - 1 && c == NCHUNK - 1) term_last  = term;
        }

        a0 = b0; a1 = b1; a2 = b2; a3 = b3;
    }

    // endpoint trapezoid weights (0.5): trace sample 0 lives on lane 0,
    // sample NT-1 on lane 63 — correct only there.
    if (ln == 0)  acc -= 0.5f * term_first;
    if (ln == 63) acc -= 0.5f * term_last;

    // ---- wave reduction, no LDS / no barrier ----
#pragma unroll
    for (int d = 32; d >= 1; d >>= 1) acc += __shfl_down(acc, d, 64);
    if (ln == 0) out[trace] = acc * dt;
}

extern "C" void kernel_launch(void* const* d_in, const int* in_sizes, int n_in,
                              void* d_out, int out_size, void* d_ws, size_t ws_size,
                              hipStream_t stream) {
    const float* f      = (const float*)d_in[0];
    const float* t      = (const float*)d_in[1];
    const float* knots  = (const float*)d_in[2];
    const float* coeffs = (const float*)d_in[3];
    float* out          = (float*)d_out;

    const int traces = in_sizes[0] / NT;          // 2048
    const int blocks = traces / WPB;              // 512
    w2loss_kernel<<<blocks, NTHREADS, 0, stream>>>(f, t, knots, coeffs, out);
}